// Round 2
// baseline (45.130 us; speedup 1.0000x reference)
//
#include <hip/hip_runtime.h>
#include <hip/hip_fp16.h>

#define IN_F   4096
#define OUT_F  11008
#define BATCH  16
#define GROUPS 32          // 4096 / 128
#define PACKED_PER_ROW (IN_F / 2)   // 2048 int32 per output row

typedef __attribute__((ext_vector_type(8))) _Float16 half8;
typedef __attribute__((ext_vector_type(4))) float    float4_t;
typedef __attribute__((ext_vector_type(4))) int      int4_t;

// One wave computes a 16(b) x 16(o) f32 tile over a 256-col K-slice via
// mfma_f32_16x16x32_f16. Weights are dequantized int4 -> f16 in registers:
// lane l loads qw[o = l&15][p = kbase/2 + (l>>4)*4 .. +3] as one dwordx4,
// whose 8 nibbles are exactly the lane's 8 B-fragment elements
// (k = kbase + (l>>4)*8 + j). A-fragment = 8 consecutive x floats.
// Any shared k-permutation between A and B placement cancels in the dot.
__global__ __launch_bounds__(256) void gptq_gemm(
    const float* __restrict__ x, const int* __restrict__ qw,
    const float* __restrict__ scales, const float* __restrict__ zeros,
    const float* __restrict__ bias, float* __restrict__ out,
    float* __restrict__ ws_part, int S)
{
    const int tid  = threadIdx.x;
    const int lane = tid & 63;
    const int wave = tid >> 6;
    const int bid  = blockIdx.x;
    const int otile = bid / S;
    const int ks    = bid - otile * S;

    const int ln = lane & 15;   // A-row (b) / B-col (o) index
    const int lk = lane >> 4;   // k-chunk 0..3

    const int o = otile * 16 + ln;      // weight row this lane loads
    const int b = ln;                   // x row this lane loads

    const int kColsPerBlock = IN_F / S;          // S=4 -> 1024
    const int kColsPerWave  = kColsPerBlock / 4; // S=4 -> 256
    const int kc0 = ks * kColsPerBlock + wave * kColsPerWave;

    const int*   qrow = qw + o * PACKED_PER_ROW;
    const float* xrow = x + b * IN_F;
    const float* srow = scales + o * GROUPS;
    const float* zrow = zeros  + o * GROUPS;

    float4_t acc = {0.f, 0.f, 0.f, 0.f};

    const int nGroups = kColsPerWave / 128;      // S=4 -> 2
    for (int gi = 0; gi < nGroups; ++gi) {
        const int gc = kc0 + gi * 128;           // group-aligned col base
        const int g  = gc >> 7;
        const float s  = srow[g];
        const float c0 = -zrow[g] * s;           // w = q*s + c0
        #pragma unroll
        for (int st = 0; st < 4; ++st) {
            const int kc = gc + st * 32;
            // B operand: 4 packed int32 = 8 nibbles = lane's 8 f16 elems
            const int4_t v = *(const int4_t*)(qrow + (kc >> 1) + lk * 4);
            // A operand: 8 consecutive x floats
            const float4_t x0 = *(const float4_t*)(xrow + kc + lk * 8);
            const float4_t x1 = *(const float4_t*)(xrow + kc + lk * 8 + 4);

            half8 af, bf;
            af[0] = (_Float16)x0.x; af[1] = (_Float16)x0.y;
            af[2] = (_Float16)x0.z; af[3] = (_Float16)x0.w;
            af[4] = (_Float16)x1.x; af[5] = (_Float16)x1.y;
            af[6] = (_Float16)x1.z; af[7] = (_Float16)x1.w;

            #pragma unroll
            for (int i = 0; i < 4; ++i) {
                const int   pv = v[i];             // byte pair of nibbles
                const float q0 = (float)(pv & 15);
                const float q1 = (float)((pv >> 4) & 15);
                bf[2*i]   = (_Float16)fmaf(q0, s, c0);
                bf[2*i+1] = (_Float16)fmaf(q1, s, c0);
            }
            acc = __builtin_amdgcn_mfma_f32_16x16x32_f16(af, bf, acc, 0, 0, 0);
        }
    }

    // Block reduction: 4 waves hold partial 16x16 tiles for disjoint K-slices.
    // C/D layout (m89-verified): lane holds D[(l>>4)*4 + r][l&15].
    __shared__ float red[4][16][16];
    #pragma unroll
    for (int r = 0; r < 4; ++r) red[wave][lk * 4 + r][ln] = acc[r];
    __syncthreads();

    const int row = tid >> 4;    // b
    const int col = tid & 15;    // o within tile
    const float sum = red[0][row][col] + red[1][row][col]
                    + red[2][row][col] + red[3][row][col];
    const int oo = otile * 16 + col;
    if (S == 1) {
        out[row * OUT_F + oo] = sum + bias[oo];
    } else {
        ws_part[(ks * BATCH + row) * OUT_F + oo] = sum;
    }
}

__global__ __launch_bounds__(256) void gptq_reduce(
    const float* __restrict__ ws_part, const float* __restrict__ bias,
    float* __restrict__ out, int S)
{
    const int idx = blockIdx.x * 256 + threadIdx.x;   // b*OUT_F + o
    if (idx >= BATCH * OUT_F) return;
    const int o = idx % OUT_F;
    float sum = bias[o];
    for (int ks = 0; ks < S; ++ks)
        sum += ws_part[ks * (BATCH * OUT_F) + idx];
    out[idx] = sum;
}

extern "C" void kernel_launch(void* const* d_in, const int* in_sizes, int n_in,
                              void* d_out, int out_size, void* d_ws, size_t ws_size,
                              hipStream_t stream) {
    const float* x      = (const float*)d_in[0];
    const int*   qwgt   = (const int*)d_in[1];
    const float* scales = (const float*)d_in[2];
    const float* zeros  = (const float*)d_in[3];
    const float* bias   = (const float*)d_in[4];
    float* out = (float*)d_out;
    float* ws  = (float*)d_ws;

    const size_t needS4 = (size_t)4 * BATCH * OUT_F * sizeof(float);
    const int S = (ws && ws_size >= needS4) ? 4 : 1;   // split-K factor

    const int nOTiles = OUT_F / 16;                    // 688
    hipLaunchKernelGGL(gptq_gemm, dim3(nOTiles * S), dim3(256), 0, stream,
                       x, qwgt, scales, zeros, bias, out, ws, S);
    if (S > 1) {
        hipLaunchKernelGGL(gptq_reduce, dim3((BATCH * OUT_F + 255) / 256),
                           dim3(256), 0, stream, ws, bias, out, S);
    }
}

// Round 3
// 36.172 us; speedup vs baseline: 1.2477x; 1.2477x over previous
//
#include <hip/hip_runtime.h>
#include <hip/hip_fp16.h>

#define IN_F   4096
#define OUT_F  11008
#define BATCH  16
#define GROUPS 32                    // 4096 / 128
#define PACKED_PER_ROW (IN_F / 2)    // 2048 int32 per output row

typedef __attribute__((ext_vector_type(8))) _Float16 half8;
typedef __attribute__((ext_vector_type(4))) _Float16 half4;
typedef __attribute__((ext_vector_type(2))) _Float16 h2;
typedef __attribute__((ext_vector_type(4))) float    float4_t;
typedef __attribute__((ext_vector_type(4))) int      int4_t;
typedef __attribute__((ext_vector_type(4))) unsigned uint4_t;

// ---- pre-pass: x (16x4096 f32) -> f16 table in workspace (128 KB) ----
__global__ __launch_bounds__(256) void xcvt(const float* __restrict__ x,
                                            _Float16* __restrict__ xh) {
    const int i = (blockIdx.x * 256 + threadIdx.x) * 4;   // 64 blocks cover 65536
    const float4_t v = *(const float4_t*)(x + i);
    half4 h = { (_Float16)v.x, (_Float16)v.y, (_Float16)v.z, (_Float16)v.w };
    *(half4*)(xh + i) = h;
}

// One wave computes a 16(b) x 16(o) f32 tile over a (IN_F/S/4)-col K-slice via
// mfma_f32_16x16x32_f16. Lane l loads qw[o = l&15][(kc>>1) + (l>>4)*4 .. +3]
// as one dwordx4 whose 8 nibbles are exactly the lane's 8 B-fragment elements.
// Dequant trick: 0x6400|n is f16 (1024+n) exactly; subtract 1024 (exact), then
// packed fma by (s, -z*s). Compile-time S -> full unroll -> all loads hoisted.
template<int S, bool XH>
__global__ __launch_bounds__(256) void gptq_gemm(
    const float* __restrict__ x, const _Float16* __restrict__ xh,
    const int* __restrict__ qw,
    const float* __restrict__ scales, const float* __restrict__ zeros,
    const float* __restrict__ bias, float* __restrict__ out,
    float* __restrict__ ws_part)
{
    const int tid  = threadIdx.x;
    const int lane = tid & 63;
    const int wave = tid >> 6;
    const int otile = blockIdx.x / S;
    const int ks    = blockIdx.x % S;

    const int ln = lane & 15;   // A-row (b) / B-col (o) index
    const int lk = lane >> 4;   // k-chunk 0..3

    const int o = otile * 16 + ln;

    constexpr int KCB = IN_F / S;    // cols per block
    constexpr int KCW = KCB / 4;     // cols per wave
    constexpr int NG  = KCW / 128;   // groups per wave (S=4 -> 2)
    const int kc0 = ks * KCB + wave * KCW;

    const int*   qrow = qw + o * PACKED_PER_ROW;
    const float* srow = scales + o * GROUPS;
    const float* zrow = zeros  + o * GROUPS;

    // hoist per-group scale/zero loads
    float sArr[NG], zArr[NG];
    #pragma unroll
    for (int gi = 0; gi < NG; ++gi) {
        const int g = (kc0 >> 7) + gi;
        sArr[gi] = srow[g];
        zArr[gi] = zrow[g];
    }

    float4_t acc = {0.f, 0.f, 0.f, 0.f};
    const h2 k1024 = { (_Float16)1024.0f, (_Float16)1024.0f };

    #pragma unroll
    for (int gi = 0; gi < NG; ++gi) {
        const float s  = sArr[gi];
        const float c0 = -zArr[gi] * s;           // w = q*s + c0
        const _Float16 sh = (_Float16)s, ch = (_Float16)c0;
        const h2 s2 = { sh, sh }, c2 = { ch, ch };
        const int gc = kc0 + gi * 128;
        #pragma unroll
        for (int st = 0; st < 4; ++st) {
            const int kc = gc + st * 32;
            // B operand: 4 packed int32 = 8 nibbles = lane's 8 f16 elems
            const int4_t v = *(const int4_t*)(qrow + (kc >> 1) + lk * 4);
            // A operand: 8 consecutive x values for row b=ln
            half8 af;
            if (XH) {
                af = *(const half8*)(xh + ln * IN_F + kc + lk * 8);
            } else {
                const float4_t x0 = *(const float4_t*)(x + ln * IN_F + kc + lk * 8);
                const float4_t x1 = *(const float4_t*)(x + ln * IN_F + kc + lk * 8 + 4);
                af[0] = (_Float16)x0.x; af[1] = (_Float16)x0.y;
                af[2] = (_Float16)x0.z; af[3] = (_Float16)x0.w;
                af[4] = (_Float16)x1.x; af[5] = (_Float16)x1.y;
                af[6] = (_Float16)x1.z; af[7] = (_Float16)x1.w;
            }
            uint4_t bw;
            #pragma unroll
            for (int i = 0; i < 4; ++i) {
                const unsigned pv = (unsigned)v[i];
                const unsigned t = (pv & 0xFu) | ((pv << 12) & 0xF0000u)
                                 | 0x64006400u;           // {1024+qlo, 1024+qhi}
                h2 q = __builtin_bit_cast(h2, t) - k1024; // exact {qlo, qhi}
                h2 w = q * s2 + c2;                       // pk fma
                bw[i] = __builtin_bit_cast(unsigned, w);
            }
            const half8 bf = __builtin_bit_cast(half8, bw);
            acc = __builtin_amdgcn_mfma_f32_16x16x32_f16(af, bf, acc, 0, 0, 0);
        }
    }

    // Block reduction: 4 waves hold partial 16x16 tiles for disjoint K-slices.
    // C/D layout (m89-verified): lane holds D[(l>>4)*4 + r][l&15].
    __shared__ float red[4][16][17];   // +1 pad: conflict-free write
    #pragma unroll
    for (int r = 0; r < 4; ++r) red[wave][lk * 4 + r][ln] = acc[r];
    __syncthreads();

    const int row = tid >> 4;    // b
    const int col = tid & 15;    // o within tile
    const float sum = red[0][row][col] + red[1][row][col]
                    + red[2][row][col] + red[3][row][col];
    const int oo = otile * 16 + col;
    if (S == 1) {
        out[row * OUT_F + oo] = sum + bias[oo];
    } else {
        ws_part[(ks * BATCH + row) * OUT_F + oo] = sum;
    }
}

__global__ __launch_bounds__(256) void gptq_reduce(
    const float* __restrict__ ws_part, const float* __restrict__ bias,
    float* __restrict__ out, int S)
{
    const int idx = blockIdx.x * 256 + threadIdx.x;   // b*OUT_F + o
    if (idx >= BATCH * OUT_F) return;
    const int o = idx % OUT_F;
    float sum = bias[o];
    for (int ks = 0; ks < S; ++ks)
        sum += ws_part[ks * (BATCH * OUT_F) + idx];
    out[idx] = sum;
}

extern "C" void kernel_launch(void* const* d_in, const int* in_sizes, int n_in,
                              void* d_out, int out_size, void* d_ws, size_t ws_size,
                              hipStream_t stream) {
    const float* x      = (const float*)d_in[0];
    const int*   qwgt   = (const int*)d_in[1];
    const float* scales = (const float*)d_in[2];
    const float* zeros  = (const float*)d_in[3];
    const float* bias   = (const float*)d_in[4];
    float* out = (float*)d_out;

    const int nOTiles = OUT_F / 16;                    // 688
    const size_t need = (size_t)8 << 20;               // partials + xh + slack

    if (d_ws && ws_size >= need) {
        float*    ws_part = (float*)d_ws;                         // 2.75 MB
        _Float16* xh      = (_Float16*)((char*)d_ws + (4 << 20)); // 128 KB
        constexpr int S = 4;
        hipLaunchKernelGGL(xcvt, dim3(BATCH * IN_F / 1024), dim3(256), 0, stream,
                           x, xh);
        hipLaunchKernelGGL((gptq_gemm<S, true>), dim3(nOTiles * S), dim3(256),
                           0, stream, x, xh, qwgt, scales, zeros, bias, out,
                           ws_part);
        hipLaunchKernelGGL(gptq_reduce, dim3((BATCH * OUT_F + 255) / 256),
                           dim3(256), 0, stream, ws_part, bias, out, S);
    } else {
        hipLaunchKernelGGL((gptq_gemm<1, false>), dim3(nOTiles), dim3(256),
                           0, stream, x, (const _Float16*)nullptr, qwgt,
                           scales, zeros, bias, out, (float*)nullptr);
    }
}